// Round 1
// 226.801 us; speedup vs baseline: 1.0075x; 1.0075x over previous
//
#include <hip/hip_runtime.h>
#include <math.h>

namespace {

constexpr int Himg = 224, Wimg = 224, Cn = 3, Kk = 32;
constexpr int MAXT = 64;
constexpr int WSTRIDE = 512;               // ints per image in tap workspace
constexpr int IMG_F  = Himg * Wimg * Cn;   // 150528 floats per image
constexpr int ROW_F  = Wimg * Cn;          // 672 floats per row (== 0 mod 4)
constexpr int ROW_B  = ROW_F * 4;          // 2688 B

constexpr int IN_CH  = 144;                // interior chunk-cols: k in [12,156)
constexpr int ED_CH  = 24;                 // edge chunk-cols: k<12 or k>=156
constexpr int IN_PER_IMG = Himg * IN_CH;   // 32256
constexpr int ED_PER_IMG = Himg * ED_CH;   // 5376
constexpr int IN_BLK = IN_PER_IMG / 256;   // 126
constexpr int ED_BLK = ED_PER_IMG / 256;   // 21
constexpr int BLK_PER_IMG = IN_BLK + ED_BLK;  // 147
// interior blocks c in [9,117) have all rows y in [16,208) -> no vertical mask
constexpr int FAST_LO = 9, FAST_HI = 117;

typedef float v4  __attribute__((ext_vector_type(4), aligned(4)));
typedef float v4a __attribute__((ext_vector_type(4), aligned(16)));

// ws per-image layout (ints): [0]=n  [1]=w  [2..65]=dky  [66..129]=dkx  [130..193]=xoff(bytes)

// ---------------- pre-pass: one tap list per image ----------------
__global__ __launch_bounds__(64)
void build_taps(const float* __restrict__ tbl,
                const int* __restrict__ amt,
                const int* __restrict__ ang,
                int* __restrict__ ws)
{
    const int b   = blockIdx.x;
    const int tid = threadIdx.x;

    __shared__ int   s_cnt;
    __shared__ float s_w;
    __shared__ int   s_dky[MAXT], s_dkx[MAXT];

    if (tid == 0) { s_cnt = 0; s_w = 0.0f; }
    __syncthreads();

    const int a = amt[b];
    // reference-exact numerics (verified absmax 0.0039 in R1-R5)
    const float  rad = (float)ang[b] * (float)(M_PI / 180.0);
    const double rd  = (double)rad;
    const float  cth = (float)cos(rd);
    const float  sth = (float)sin(rd);
    const float  e   = 31.0f;
    const float xoff = __fmul_rn(__fsub_rn(e, __fsub_rn(__fmul_rn(cth, e), __fmul_rn(sth, e))), 0.5f);
    const float yoff = __fmul_rn(__fsub_rn(e, __fadd_rn(__fmul_rn(sth, e), __fmul_rn(cth, e))), 0.5f);

    for (int p = tid; p < Kk * Kk; p += 64) {
        const int   ky = p >> 5, kx = p & 31;
        const float xf = (float)kx, yf = (float)ky;
        const float sx = __fadd_rn(__fsub_rn(__fmul_rn(cth, xf), __fmul_rn(sth, yf)), xoff);
        const float sy = __fadd_rn(__fadd_rn(__fmul_rn(sth, xf), __fmul_rn(cth, yf)), yoff);
        const int ix = (int)rintf(sx);   // round-half-even == jnp.round
        const int iy = (int)rintf(sy);
        if (ix >= 0 && ix < Kk && iy >= 0 && iy < Kk) {
            const float v = tbl[((a * Kk + iy) * Kk + ix) * Cn];
            if (v != 0.0f) {
                const int idx = atomicAdd(&s_cnt, 1);
                if (idx < MAXT) {
                    s_dky[idx] = ky - 15;
                    s_dkx[idx] = kx - 15;
                    s_w = v;                 // benign race: all writers store 1/size
                }
            }
        }
    }
    __syncthreads();

    const int n = min(s_cnt, MAXT);
    int* wsb = ws + b * WSTRIDE;
    if (tid == 0) { wsb[0] = n; wsb[1] = __float_as_int(s_w); }
    for (int i = tid; i < n; i += 64) {
        wsb[2 + i]   = s_dky[i];
        wsb[66 + i]  = s_dkx[i];
        wsb[130 + i] = s_dky[i] * ROW_B + s_dkx[i] * (int)(Cn * sizeof(float));
    }
}

// ---------------- conv directly from x, flat-space contiguous loads ----------------
__global__ __launch_bounds__(256)
void blur_direct(const float* __restrict__ x,
                 const int* __restrict__ ws,
                 float* __restrict__ out,
                 int B)
{
    const int tid = threadIdx.x;
    const int L   = blockIdx.x;

    // XCD-pinned decode: image b handled entirely by XCD (b & 7), blocks of an
    // image adjacent in dispatch order (heuristic: linear id -> XCD round-robin).
    int b, c;
    if (B == 128) {
        const int xcd = L & 7;
        const int j   = L >> 3;                 // [0, 16*147)
        const int g   = j / BLK_PER_IMG;        // image group on this XCD
        c = j - g * BLK_PER_IMG;
        b = g * 8 + xcd;
    } else {
        b = L / BLK_PER_IMG;
        c = L - b * BLK_PER_IMG;
    }

    __shared__ int shNW[2];
    __shared__ int s_dky[MAXT], s_dkx[MAXT], s_xoff[MAXT];
    const int* wsb = ws + b * WSTRIDE;
    if (tid < 2)    shNW[tid]   = wsb[tid];
    if (tid < MAXT) {
        s_dky[tid]  = wsb[2 + tid];
        s_dkx[tid]  = wsb[66 + tid];
        s_xoff[tid] = wsb[130 + tid];
    }
    __syncthreads();

    const int   n = shNW[0];
    const float w = __int_as_float(shNW[1]);
    const float* xb = x + (size_t)b * IMG_F;

    if (c < IN_BLK) {
        // ---- interior chunk-columns: contiguous dwordx4 per tap ----
        const int ii = c * 256 + tid;
        const int y  = ii / IN_CH;
        const int k  = ii - y * IN_CH + 12;     // [12, 156)
        const int fbase = y * ROW_F + 4 * k;
        const char* base = (const char*)xb + (size_t)fbase * 4;

        float a0 = 0.0f, a1 = 0.0f, a2 = 0.0f, a3 = 0.0f;

        if (c >= FAST_LO && c < FAST_HI) {
            // fast path: all taps in-bounds, unroll 8 (8 dwordx4 in flight)
            int i = 0;
            for (; i + 8 <= n; i += 8) {
                const v4 f0 = *(const v4*)(base + s_xoff[i]);
                const v4 f1 = *(const v4*)(base + s_xoff[i + 1]);
                const v4 f2 = *(const v4*)(base + s_xoff[i + 2]);
                const v4 f3 = *(const v4*)(base + s_xoff[i + 3]);
                const v4 f4 = *(const v4*)(base + s_xoff[i + 4]);
                const v4 f5 = *(const v4*)(base + s_xoff[i + 5]);
                const v4 f6 = *(const v4*)(base + s_xoff[i + 6]);
                const v4 f7 = *(const v4*)(base + s_xoff[i + 7]);
                // accumulation stays tap-ascending per component (numerics-identical)
                a0 += f0.x; a1 += f0.y; a2 += f0.z; a3 += f0.w;
                a0 += f1.x; a1 += f1.y; a2 += f1.z; a3 += f1.w;
                a0 += f2.x; a1 += f2.y; a2 += f2.z; a3 += f2.w;
                a0 += f3.x; a1 += f3.y; a2 += f3.z; a3 += f3.w;
                a0 += f4.x; a1 += f4.y; a2 += f4.z; a3 += f4.w;
                a0 += f5.x; a1 += f5.y; a2 += f5.z; a3 += f5.w;
                a0 += f6.x; a1 += f6.y; a2 += f6.z; a3 += f6.w;
                a0 += f7.x; a1 += f7.y; a2 += f7.z; a3 += f7.w;
            }
            if (i + 4 <= n) {
                const v4 f0 = *(const v4*)(base + s_xoff[i]);
                const v4 f1 = *(const v4*)(base + s_xoff[i + 1]);
                const v4 f2 = *(const v4*)(base + s_xoff[i + 2]);
                const v4 f3 = *(const v4*)(base + s_xoff[i + 3]);
                a0 += f0.x; a1 += f0.y; a2 += f0.z; a3 += f0.w;
                a0 += f1.x; a1 += f1.y; a2 += f1.z; a3 += f1.w;
                a0 += f2.x; a1 += f2.y; a2 += f2.z; a3 += f2.w;
                a0 += f3.x; a1 += f3.y; a2 += f3.z; a3 += f3.w;
                i += 4;
            }
            for (; i < n; ++i) {
                const v4 f = *(const v4*)(base + s_xoff[i]);
                a0 += f.x; a1 += f.y; a2 += f.z; a3 += f.w;
            }
        } else {
            // y-edge blocks: per-lane row mask, branchless, unroll 4 (was 1 in flight)
            int i = 0;
            for (; i + 4 <= n; i += 4) {
                const int  r0 = y + s_dky[i];     const bool ok0 = (unsigned)r0 < (unsigned)Himg;
                const int  r1 = y + s_dky[i + 1]; const bool ok1 = (unsigned)r1 < (unsigned)Himg;
                const int  r2 = y + s_dky[i + 2]; const bool ok2 = (unsigned)r2 < (unsigned)Himg;
                const int  r3 = y + s_dky[i + 3]; const bool ok3 = (unsigned)r3 < (unsigned)Himg;
                const v4 f0 = *(const v4*)(base + (ok0 ? s_xoff[i]     : 0));
                const v4 f1 = *(const v4*)(base + (ok1 ? s_xoff[i + 1] : 0));
                const v4 f2 = *(const v4*)(base + (ok2 ? s_xoff[i + 2] : 0));
                const v4 f3 = *(const v4*)(base + (ok3 ? s_xoff[i + 3] : 0));
                const float m0 = ok0 ? 1.0f : 0.0f;
                const float m1 = ok1 ? 1.0f : 0.0f;
                const float m2 = ok2 ? 1.0f : 0.0f;
                const float m3 = ok3 ? 1.0f : 0.0f;
                a0 += m0 * f0.x; a1 += m0 * f0.y; a2 += m0 * f0.z; a3 += m0 * f0.w;
                a0 += m1 * f1.x; a1 += m1 * f1.y; a2 += m1 * f1.z; a3 += m1 * f1.w;
                a0 += m2 * f2.x; a1 += m2 * f2.y; a2 += m2 * f2.z; a3 += m2 * f2.w;
                a0 += m3 * f3.x; a1 += m3 * f3.y; a2 += m3 * f3.z; a3 += m3 * f3.w;
            }
            for (; i < n; ++i) {
                const int  row = y + s_dky[i];
                const bool ok  = (unsigned)row < (unsigned)Himg;
                const int  off = ok ? s_xoff[i] : 0;      // base+0 = own chunk (in-bounds)
                const float m  = ok ? 1.0f : 0.0f;
                const v4 f = *(const v4*)(base + off);
                a0 += m * f.x; a1 += m * f.y; a2 += m * f.z; a3 += m * f.w;
            }
        }

        float* o = out + (size_t)b * IMG_F + fbase;
        __builtin_nontemporal_store(v4a{a0 * w, a1 * w, a2 * w, a3 * w}, (v4a*)o);
    } else {
        // ---- x-edge chunk-columns: masked scalar loads, 2-tap unroll (8 loads in flight) ----
        const int ee = (c - IN_BLK) * 256 + tid;
        const int y  = ee / ED_CH;
        const int j  = ee - y * ED_CH;
        const int k  = (j < 12) ? j : (j + 144);   // [0,12) U [156,168)
        const int fd0 = 4 * k;

        float acc[4] = {0.0f, 0.0f, 0.0f, 0.0f};
        int i = 0;
        for (; i + 2 <= n; i += 2) {
            const int  r0  = y + s_dky[i];
            const int  r1  = y + s_dky[i + 1];
            const bool rk0 = (unsigned)r0 < (unsigned)Himg;
            const bool rk1 = (unsigned)r1 < (unsigned)Himg;
            const int  s00 = fd0 + 3 * s_dkx[i];
            const int  s01 = fd0 + 3 * s_dkx[i + 1];
            const int  ob0 = r0 * ROW_F + s00;
            const int  ob1 = r1 * ROW_F + s01;
#pragma unroll
            for (int q = 0; q < 4; ++q) {
                const bool ok0 = rk0 & ((unsigned)(s00 + q) < (unsigned)ROW_F);
                const bool ok1 = rk1 & ((unsigned)(s01 + q) < (unsigned)ROW_F);
                const float u0 = xb[ok0 ? (ob0 + q) : 0];
                const float u1 = xb[ok1 ? (ob1 + q) : 0];
                acc[q] += ok0 ? u0 : 0.0f;   // tap order preserved: i before i+1
                acc[q] += ok1 ? u1 : 0.0f;
            }
        }
        for (; i < n; ++i) {
            const int  row = y + s_dky[i];
            const bool rok = (unsigned)row < (unsigned)Himg;
            const int  s0  = fd0 + 3 * s_dkx[i];
            const int  ob  = row * ROW_F + s0;
#pragma unroll
            for (int q = 0; q < 4; ++q) {
                const bool ok  = rok & ((unsigned)(s0 + q) < (unsigned)ROW_F);
                const int  off = ok ? (ob + q) : 0;
                const float v  = xb[off];
                acc[q] += ok ? v : 0.0f;
            }
        }

        float* o = out + (size_t)b * IMG_F + (size_t)y * ROW_F + fd0;
        __builtin_nontemporal_store(
            v4a{acc[0] * w, acc[1] * w, acc[2] * w, acc[3] * w}, (v4a*)o);
    }
}

}  // namespace

extern "C" void kernel_launch(void* const* d_in, const int* in_sizes, int n_in,
                              void* d_out, int out_size, void* d_ws, size_t ws_size,
                              hipStream_t stream) {
    const float* x   = (const float*)d_in[0];
    const float* tbl = (const float*)d_in[1];
    const int*   amt = (const int*)d_in[2];
    const int*   ang = (const int*)d_in[3];
    float*       out = (float*)d_out;
    int*         ws  = (int*)d_ws;

    const int B = in_sizes[2];  // 128

    build_taps<<<B, 64, 0, stream>>>(tbl, amt, ang, ws);
    blur_direct<<<B * BLK_PER_IMG, 256, 0, stream>>>(x, ws, out, B);
}

// Round 2
// 226.590 us; speedup vs baseline: 1.0084x; 1.0009x over previous
//
#include <hip/hip_runtime.h>
#include <math.h>

namespace {

constexpr int Himg = 224, Wimg = 224, Cn = 3, Kk = 32;
constexpr int MAXT = 64;
constexpr int WSTRIDE = 512;               // ints per image in tap workspace
constexpr int IMG_F  = Himg * Wimg * Cn;   // 150528 floats per image
constexpr int ROW_F  = Wimg * Cn;          // 672 floats per row (== 0 mod 4)
constexpr int ROW_B  = ROW_F * 4;          // 2688 B

constexpr int IN_CH  = 144;                // interior chunk-cols: k in [12,156)
constexpr int ED_CH  = 24;                 // edge chunk-cols: k<12 or k>=156
constexpr int IN_PER_IMG = Himg * IN_CH;   // 32256
constexpr int ED_PER_IMG = Himg * ED_CH;   // 5376
constexpr int IN_BLK = IN_PER_IMG / 256;   // 126
constexpr int ED_BLK = ED_PER_IMG / 256;   // 21
constexpr int BLK_PER_IMG = IN_BLK + ED_BLK;  // 147
// interior blocks c in [9,117) have all rows y in [16,208) -> no vertical mask
constexpr int FAST_LO = 9, FAST_HI = 117;

typedef float v4  __attribute__((ext_vector_type(4), aligned(4)));
typedef float v4a __attribute__((ext_vector_type(4), aligned(16)));

// ws per-image layout (ints): [0]=n  [1]=w  [2..65]=dky  [66..129]=dkx  [130..193]=xoff(bytes)

// ---------------- pre-pass: one tap list per image ----------------
__global__ __launch_bounds__(64)
void build_taps(const float* __restrict__ tbl,
                const int* __restrict__ amt,
                const int* __restrict__ ang,
                int* __restrict__ ws)
{
    const int b   = blockIdx.x;
    const int tid = threadIdx.x;

    __shared__ int   s_cnt;
    __shared__ float s_w;
    __shared__ int   s_dky[MAXT], s_dkx[MAXT];

    if (tid == 0) { s_cnt = 0; s_w = 0.0f; }
    __syncthreads();

    const int a = amt[b];
    // reference-exact numerics (verified absmax 0.0039 in R1-R5)
    const float  rad = (float)ang[b] * (float)(M_PI / 180.0);
    const double rd  = (double)rad;
    const float  cth = (float)cos(rd);
    const float  sth = (float)sin(rd);
    const float  e   = 31.0f;
    const float xoff = __fmul_rn(__fsub_rn(e, __fsub_rn(__fmul_rn(cth, e), __fmul_rn(sth, e))), 0.5f);
    const float yoff = __fmul_rn(__fsub_rn(e, __fadd_rn(__fmul_rn(sth, e), __fmul_rn(cth, e))), 0.5f);

    for (int p = tid; p < Kk * Kk; p += 64) {
        const int   ky = p >> 5, kx = p & 31;
        const float xf = (float)kx, yf = (float)ky;
        const float sx = __fadd_rn(__fsub_rn(__fmul_rn(cth, xf), __fmul_rn(sth, yf)), xoff);
        const float sy = __fadd_rn(__fadd_rn(__fmul_rn(sth, xf), __fmul_rn(cth, yf)), yoff);
        const int ix = (int)rintf(sx);   // round-half-even == jnp.round
        const int iy = (int)rintf(sy);
        if (ix >= 0 && ix < Kk && iy >= 0 && iy < Kk) {
            const float v = tbl[((a * Kk + iy) * Kk + ix) * Cn];
            if (v != 0.0f) {
                const int idx = atomicAdd(&s_cnt, 1);
                if (idx < MAXT) {
                    s_dky[idx] = ky - 15;
                    s_dkx[idx] = kx - 15;
                    s_w = v;                 // benign race: all writers store 1/size
                }
            }
        }
    }
    __syncthreads();

    const int n = min(s_cnt, MAXT);
    int* wsb = ws + b * WSTRIDE;
    if (tid == 0) { wsb[0] = n; wsb[1] = __float_as_int(s_w); }
    for (int i = tid; i < n; i += 64) {
        wsb[2 + i]   = s_dky[i];
        wsb[66 + i]  = s_dkx[i];
        wsb[130 + i] = s_dky[i] * ROW_B + s_dkx[i] * (int)(Cn * sizeof(float));
    }
}

// ---------------- conv directly from x, flat-space contiguous loads ----------------
// __launch_bounds__(256, 2): min 2 waves/EU -> VGPR cap 256. The default cap
// (occupancy-greedy) pinned VGPR_Count at 40, which forced the register
// allocator to serialize the 8-deep load batches back to ~3 outstanding.
// Measured occupancy is ~4 waves/SIMD anyway, so trading VGPRs for real
// memory-level parallelism is free.
__global__ __launch_bounds__(256, 2)
void blur_direct(const float* __restrict__ x,
                 const int* __restrict__ ws,
                 float* __restrict__ out,
                 int B)
{
    const int tid = threadIdx.x;
    const int L   = blockIdx.x;

    // XCD-pinned decode: image b handled entirely by XCD (b & 7), blocks of an
    // image adjacent in dispatch order (heuristic: linear id -> XCD round-robin).
    int b, c;
    if (B == 128) {
        const int xcd = L & 7;
        const int j   = L >> 3;                 // [0, 16*147)
        const int g   = j / BLK_PER_IMG;        // image group on this XCD
        c = j - g * BLK_PER_IMG;
        b = g * 8 + xcd;
    } else {
        b = L / BLK_PER_IMG;
        c = L - b * BLK_PER_IMG;
    }

    __shared__ int shNW[2];
    __shared__ int s_dky[MAXT], s_dkx[MAXT], s_xoff[MAXT];
    const int* wsb = ws + b * WSTRIDE;
    if (tid < 2)    shNW[tid]   = wsb[tid];
    if (tid < MAXT) {
        s_dky[tid]  = wsb[2 + tid];
        s_dkx[tid]  = wsb[66 + tid];
        s_xoff[tid] = wsb[130 + tid];
    }
    __syncthreads();

    const int   n = shNW[0];
    const float w = __int_as_float(shNW[1]);
    const float* xb = x + (size_t)b * IMG_F;

    if (c < IN_BLK) {
        // ---- interior chunk-columns: contiguous dwordx4 per tap ----
        const int ii = c * 256 + tid;
        const int y  = ii / IN_CH;
        const int k  = ii - y * IN_CH + 12;     // [12, 156)
        const int fbase = y * ROW_F + 4 * k;
        const char* base = (const char*)xb + (size_t)fbase * 4;

        float a0 = 0.0f, a1 = 0.0f, a2 = 0.0f, a3 = 0.0f;

        if (c >= FAST_LO && c < FAST_HI) {
            // fast path: all taps in-bounds, unroll 8 (8 dwordx4 in flight)
            int i = 0;
            for (; i + 8 <= n; i += 8) {
                const v4 f0 = *(const v4*)(base + s_xoff[i]);
                const v4 f1 = *(const v4*)(base + s_xoff[i + 1]);
                const v4 f2 = *(const v4*)(base + s_xoff[i + 2]);
                const v4 f3 = *(const v4*)(base + s_xoff[i + 3]);
                const v4 f4 = *(const v4*)(base + s_xoff[i + 4]);
                const v4 f5 = *(const v4*)(base + s_xoff[i + 5]);
                const v4 f6 = *(const v4*)(base + s_xoff[i + 6]);
                const v4 f7 = *(const v4*)(base + s_xoff[i + 7]);
                // accumulation stays tap-ascending per component (numerics-identical)
                a0 += f0.x; a1 += f0.y; a2 += f0.z; a3 += f0.w;
                a0 += f1.x; a1 += f1.y; a2 += f1.z; a3 += f1.w;
                a0 += f2.x; a1 += f2.y; a2 += f2.z; a3 += f2.w;
                a0 += f3.x; a1 += f3.y; a2 += f3.z; a3 += f3.w;
                a0 += f4.x; a1 += f4.y; a2 += f4.z; a3 += f4.w;
                a0 += f5.x; a1 += f5.y; a2 += f5.z; a3 += f5.w;
                a0 += f6.x; a1 += f6.y; a2 += f6.z; a3 += f6.w;
                a0 += f7.x; a1 += f7.y; a2 += f7.z; a3 += f7.w;
            }
            if (i + 4 <= n) {
                const v4 f0 = *(const v4*)(base + s_xoff[i]);
                const v4 f1 = *(const v4*)(base + s_xoff[i + 1]);
                const v4 f2 = *(const v4*)(base + s_xoff[i + 2]);
                const v4 f3 = *(const v4*)(base + s_xoff[i + 3]);
                a0 += f0.x; a1 += f0.y; a2 += f0.z; a3 += f0.w;
                a0 += f1.x; a1 += f1.y; a2 += f1.z; a3 += f1.w;
                a0 += f2.x; a1 += f2.y; a2 += f2.z; a3 += f2.w;
                a0 += f3.x; a1 += f3.y; a2 += f3.z; a3 += f3.w;
                i += 4;
            }
            for (; i < n; ++i) {
                const v4 f = *(const v4*)(base + s_xoff[i]);
                a0 += f.x; a1 += f.y; a2 += f.z; a3 += f.w;
            }
        } else {
            // y-edge blocks: per-lane row mask, branchless, unroll 4
            int i = 0;
            for (; i + 4 <= n; i += 4) {
                const int  r0 = y + s_dky[i];     const bool ok0 = (unsigned)r0 < (unsigned)Himg;
                const int  r1 = y + s_dky[i + 1]; const bool ok1 = (unsigned)r1 < (unsigned)Himg;
                const int  r2 = y + s_dky[i + 2]; const bool ok2 = (unsigned)r2 < (unsigned)Himg;
                const int  r3 = y + s_dky[i + 3]; const bool ok3 = (unsigned)r3 < (unsigned)Himg;
                const v4 f0 = *(const v4*)(base + (ok0 ? s_xoff[i]     : 0));
                const v4 f1 = *(const v4*)(base + (ok1 ? s_xoff[i + 1] : 0));
                const v4 f2 = *(const v4*)(base + (ok2 ? s_xoff[i + 2] : 0));
                const v4 f3 = *(const v4*)(base + (ok3 ? s_xoff[i + 3] : 0));
                const float m0 = ok0 ? 1.0f : 0.0f;
                const float m1 = ok1 ? 1.0f : 0.0f;
                const float m2 = ok2 ? 1.0f : 0.0f;
                const float m3 = ok3 ? 1.0f : 0.0f;
                a0 += m0 * f0.x; a1 += m0 * f0.y; a2 += m0 * f0.z; a3 += m0 * f0.w;
                a0 += m1 * f1.x; a1 += m1 * f1.y; a2 += m1 * f1.z; a3 += m1 * f1.w;
                a0 += m2 * f2.x; a1 += m2 * f2.y; a2 += m2 * f2.z; a3 += m2 * f2.w;
                a0 += m3 * f3.x; a1 += m3 * f3.y; a2 += m3 * f3.z; a3 += m3 * f3.w;
            }
            for (; i < n; ++i) {
                const int  row = y + s_dky[i];
                const bool ok  = (unsigned)row < (unsigned)Himg;
                const int  off = ok ? s_xoff[i] : 0;      // base+0 = own chunk (in-bounds)
                const float m  = ok ? 1.0f : 0.0f;
                const v4 f = *(const v4*)(base + off);
                a0 += m * f.x; a1 += m * f.y; a2 += m * f.z; a3 += m * f.w;
            }
        }

        float* o = out + (size_t)b * IMG_F + fbase;
        __builtin_nontemporal_store(v4a{a0 * w, a1 * w, a2 * w, a3 * w}, (v4a*)o);
    } else {
        // ---- x-edge chunk-columns: masked scalar loads, 2-tap unroll ----
        const int ee = (c - IN_BLK) * 256 + tid;
        const int y  = ee / ED_CH;
        const int j  = ee - y * ED_CH;
        const int k  = (j < 12) ? j : (j + 144);   // [0,12) U [156,168)
        const int fd0 = 4 * k;

        float acc[4] = {0.0f, 0.0f, 0.0f, 0.0f};
        int i = 0;
        for (; i + 2 <= n; i += 2) {
            const int  r0  = y + s_dky[i];
            const int  r1  = y + s_dky[i + 1];
            const bool rk0 = (unsigned)r0 < (unsigned)Himg;
            const bool rk1 = (unsigned)r1 < (unsigned)Himg;
            const int  s00 = fd0 + 3 * s_dkx[i];
            const int  s01 = fd0 + 3 * s_dkx[i + 1];
            const int  ob0 = r0 * ROW_F + s00;
            const int  ob1 = r1 * ROW_F + s01;
#pragma unroll
            for (int q = 0; q < 4; ++q) {
                const bool ok0 = rk0 & ((unsigned)(s00 + q) < (unsigned)ROW_F);
                const bool ok1 = rk1 & ((unsigned)(s01 + q) < (unsigned)ROW_F);
                const float u0 = xb[ok0 ? (ob0 + q) : 0];
                const float u1 = xb[ok1 ? (ob1 + q) : 0];
                acc[q] += ok0 ? u0 : 0.0f;   // tap order preserved: i before i+1
                acc[q] += ok1 ? u1 : 0.0f;
            }
        }
        for (; i < n; ++i) {
            const int  row = y + s_dky[i];
            const bool rok = (unsigned)row < (unsigned)Himg;
            const int  s0  = fd0 + 3 * s_dkx[i];
            const int  ob  = row * ROW_F + s0;
#pragma unroll
            for (int q = 0; q < 4; ++q) {
                const bool ok  = rok & ((unsigned)(s0 + q) < (unsigned)ROW_F);
                const int  off = ok ? (ob + q) : 0;
                const float v  = xb[off];
                acc[q] += ok ? v : 0.0f;
            }
        }

        float* o = out + (size_t)b * IMG_F + (size_t)y * ROW_F + fd0;
        __builtin_nontemporal_store(
            v4a{acc[0] * w, acc[1] * w, acc[2] * w, acc[3] * w}, (v4a*)o);
    }
}

}  // namespace

extern "C" void kernel_launch(void* const* d_in, const int* in_sizes, int n_in,
                              void* d_out, int out_size, void* d_ws, size_t ws_size,
                              hipStream_t stream) {
    const float* x   = (const float*)d_in[0];
    const float* tbl = (const float*)d_in[1];
    const int*   amt = (const int*)d_in[2];
    const int*   ang = (const int*)d_in[3];
    float*       out = (float*)d_out;
    int*         ws  = (int*)d_ws;

    const int B = in_sizes[2];  // 128

    build_taps<<<B, 64, 0, stream>>>(tbl, amt, ang, ws);
    blur_direct<<<B * BLK_PER_IMG, 256, 0, stream>>>(x, ws, out, B);
}